// Round 1
// baseline (414.215 us; speedup 1.0000x reference)
//
#include <hip/hip_runtime.h>
#include <hip/hip_bf16.h>
#include <stdint.h>

#define B_ 32
#define T_ 128
#define S_ 2048
#define D_ 1024

typedef float floatx4 __attribute__((ext_vector_type(4)));
typedef float f32x4 __attribute__((ext_vector_type(4)));
typedef unsigned short u16x4 __attribute__((ext_vector_type(4)));
typedef unsigned short u16x8 __attribute__((ext_vector_type(8)));
typedef __bf16 bf16x8 __attribute__((ext_vector_type(8)));

__device__ __forceinline__ unsigned short f2bf(float x){
  __hip_bfloat16 h = __float2bfloat16(x);
  return __builtin_bit_cast(unsigned short, h);
}
__device__ __forceinline__ float bf2f(unsigned short u){
  __hip_bfloat16 h = __builtin_bit_cast(__hip_bfloat16, u);
  return __bfloat162float(h);
}
__device__ __forceinline__ f32x4 mfma16(u16x8 a, u16x8 b, f32x4 c){
  return __builtin_amdgcn_mfma_f32_16x16x32_bf16(
      __builtin_bit_cast(bf16x8, a), __builtin_bit_cast(bf16x8, b), c, 0, 0, 0);
}

// ---------------------------------------------------------------------------
// K1: logits[b][t][s] = sum_d src[b][t][d] * mb[b][s][d]
// Split-bf16 (hi/lo) x 3 MFMA for fp32-class accuracy.
// Tile 128(t) x 128(s), BK=64, 4 waves (2x2), each wave 64x64.
// ---------------------------------------------------------------------------
__global__ __launch_bounds__(256, 2) void k_align(
    const float* __restrict__ src, const float* __restrict__ mb,
    float* __restrict__ logits)
{
  __shared__ unsigned short Ah[128][72], Al[128][72], Bh[128][72], Bl[128][72];
  const int sblk = blockIdx.x, b = blockIdx.y;
  const int tid = threadIdx.x, lane = tid & 63, wave = tid >> 6;
  const int wr = wave >> 1, wc = wave & 1;
  const float* Ag = src + (size_t)b * T_ * D_;
  const float* Bg = mb + (size_t)b * S_ * D_ + (size_t)sblk * 128 * D_;

  f32x4 acc[4][4];
  #pragma unroll
  for (int m = 0; m < 4; m++)
    #pragma unroll
    for (int n = 0; n < 4; n++) acc[m][n] = (f32x4){0.f, 0.f, 0.f, 0.f};

  for (int k0 = 0; k0 < D_; k0 += 64) {
    __syncthreads();
    #pragma unroll
    for (int j = 0; j < 8; j++) {
      int f4 = tid + 256 * j;          // 0..2047 over [128][16 float4]
      int row = f4 >> 4, c4 = (f4 & 15) * 4;
      floatx4 va = *(const floatx4*)(Ag + (size_t)row * D_ + k0 + c4);
      floatx4 vb = *(const floatx4*)(Bg + (size_t)row * D_ + k0 + c4);
      u16x4 ah, al, bh, bl;
      #pragma unroll
      for (int i = 0; i < 4; i++) {
        unsigned short h = f2bf(va[i]); float hf = bf2f(h);
        ah[i] = h; al[i] = f2bf(va[i] - hf);
        h = f2bf(vb[i]); hf = bf2f(h);
        bh[i] = h; bl[i] = f2bf(vb[i] - hf);
      }
      *(u16x4*)&Ah[row][c4] = ah;
      *(u16x4*)&Al[row][c4] = al;
      *(u16x4*)&Bh[row][c4] = bh;
      *(u16x4*)&Bl[row][c4] = bl;
    }
    __syncthreads();
    #pragma unroll
    for (int kk = 0; kk < 2; kk++) {
      int kb = kk * 32 + ((lane >> 4) << 3);
      u16x8 a_h[4], a_l[4], b_h[4], b_l[4];
      #pragma unroll
      for (int m = 0; m < 4; m++) {
        int r = wr * 64 + m * 16 + (lane & 15);
        a_h[m] = *(const u16x8*)&Ah[r][kb];
        a_l[m] = *(const u16x8*)&Al[r][kb];
      }
      #pragma unroll
      for (int n = 0; n < 4; n++) {
        int r = wc * 64 + n * 16 + (lane & 15);
        b_h[n] = *(const u16x8*)&Bh[r][kb];
        b_l[n] = *(const u16x8*)&Bl[r][kb];
      }
      #pragma unroll
      for (int m = 0; m < 4; m++)
        #pragma unroll
        for (int n = 0; n < 4; n++) {
          acc[m][n] = mfma16(a_h[m], b_h[n], acc[m][n]);
          acc[m][n] = mfma16(a_h[m], b_l[n], acc[m][n]);
          acc[m][n] = mfma16(a_l[m], b_h[n], acc[m][n]);
        }
    }
  }
  #pragma unroll
  for (int m = 0; m < 4; m++)
    #pragma unroll
    for (int n = 0; n < 4; n++)
      #pragma unroll
      for (int j = 0; j < 4; j++) {
        int t = wr * 64 + m * 16 + ((lane >> 4) << 2) + j;
        int s = sblk * 128 + wc * 64 + n * 16 + (lane & 15);
        logits[((size_t)b * T_ + t) * S_ + s] = acc[m][n][j];
      }
}

// ---------------------------------------------------------------------------
// K2: masked softmax per (b,t) row; writes p in-place over logits (for K3)
// and transposed to out1[t][b][s]. Handles int64-or-int32 memory_lengths.
// ---------------------------------------------------------------------------
__global__ __launch_bounds__(256) void k_softmax(
    float* __restrict__ logits, const int* __restrict__ lens,
    float* __restrict__ out1)
{
  const int bt = blockIdx.x;
  const int b = bt >> 7, t = bt & 127;
  // lens >= 1 always; if stored as int64 little-endian, lens[1] (high word
  // of element 0) is 0, which is impossible for int32 data.
  const int probe = lens[1];
  const int len = (probe == 0) ? lens[2 * b] : lens[b];
  float* row = logits + (size_t)bt * S_;
  const int tid = threadIdx.x, lane = tid & 63, wave = tid >> 6;

  floatx4 v[2];
  float mx = -3.0e38f;
  #pragma unroll
  for (int j = 0; j < 2; j++) {
    int f4 = tid + 256 * j;
    v[j] = *(const floatx4*)(row + f4 * 4);
    #pragma unroll
    for (int i = 0; i < 4; i++) {
      int s = f4 * 4 + i;
      if (s < len) mx = fmaxf(mx, v[j][i]);
    }
  }
  #pragma unroll
  for (int off = 1; off < 64; off <<= 1) mx = fmaxf(mx, __shfl_xor(mx, off));
  __shared__ float red[8];
  if (lane == 0) red[wave] = mx;
  __syncthreads();
  mx = fmaxf(fmaxf(red[0], red[1]), fmaxf(red[2], red[3]));

  float sum = 0.f;
  floatx4 e[2];
  #pragma unroll
  for (int j = 0; j < 2; j++) {
    int f4 = tid + 256 * j;
    #pragma unroll
    for (int i = 0; i < 4; i++) {
      int s = f4 * 4 + i;
      float ee = (s < len) ? __expf(v[j][i] - mx) : 0.f;
      e[j][i] = ee; sum += ee;
    }
  }
  #pragma unroll
  for (int off = 1; off < 64; off <<= 1) sum += __shfl_xor(sum, off);
  if (lane == 0) red[4 + wave] = sum;
  __syncthreads();
  sum = red[4] + red[5] + red[6] + red[7];
  const float inv = 1.0f / sum;

  float* orow = out1 + ((size_t)t * B_ + b) * S_;
  #pragma unroll
  for (int j = 0; j < 2; j++) {
    int f4 = tid + 256 * j;
    floatx4 o;
    #pragma unroll
    for (int i = 0; i < 4; i++) o[i] = e[j][i] * inv;
    *(floatx4*)(row + f4 * 4) = o;    // in-place p, [b][t][s]
    *(floatx4*)(orow + f4 * 4) = o;   // output, [t][b][s]
  }
}

// ---------------------------------------------------------------------------
// K3: c[b][t][d] = sum_s p[b][t][s] * mb[b][s][d]. p from logits buffer
// (k-contiguous A). mb tile transposed in-register during staging so B
// fragments are contiguous ds_read_b128.
// ---------------------------------------------------------------------------
__global__ __launch_bounds__(256, 2) void k_pv(
    const float* __restrict__ p, const float* __restrict__ mb,
    float* __restrict__ cout)
{
  __shared__ unsigned short As[128][72];   // [t][s]
  __shared__ unsigned short BsT[128][72];  // [d][s]
  const int dblk = blockIdx.x, b = blockIdx.y;
  const int tid = threadIdx.x, lane = tid & 63, wave = tid >> 6;
  const int wr = wave >> 1, wc = wave & 1;
  const float* Pg = p + (size_t)b * T_ * S_;
  const float* Bg = mb + (size_t)b * S_ * D_ + dblk * 128;

  f32x4 acc[4][4];
  #pragma unroll
  for (int m = 0; m < 4; m++)
    #pragma unroll
    for (int n = 0; n < 4; n++) acc[m][n] = (f32x4){0.f, 0.f, 0.f, 0.f};

  for (int k0 = 0; k0 < S_; k0 += 64) {
    __syncthreads();
    // stage A (p): [128 t][64 s]
    #pragma unroll
    for (int j = 0; j < 8; j++) {
      int f4 = tid + 256 * j;
      int row = f4 >> 4, c4 = (f4 & 15) * 4;
      floatx4 va = *(const floatx4*)(Pg + (size_t)row * S_ + k0 + c4);
      u16x4 ah;
      #pragma unroll
      for (int i = 0; i < 4; i++) ah[i] = f2bf(va[i]);
      *(u16x4*)&As[row][c4] = ah;
    }
    // stage B transposed: [64 s][128 d] -> BsT[d][s], 4x4 reg transpose
    #pragma unroll
    for (int q = 0; q < 2; q++) {
      int g = tid + 256 * q;        // 512 groups of 4s x 4d
      int gs = g & 15, gd = g >> 4; // gd 0..31
      int s0 = gs * 4, d0 = gd * 4;
      floatx4 r0 = *(const floatx4*)(Bg + (size_t)(k0 + s0 + 0) * D_ + d0);
      floatx4 r1 = *(const floatx4*)(Bg + (size_t)(k0 + s0 + 1) * D_ + d0);
      floatx4 r2 = *(const floatx4*)(Bg + (size_t)(k0 + s0 + 2) * D_ + d0);
      floatx4 r3 = *(const floatx4*)(Bg + (size_t)(k0 + s0 + 3) * D_ + d0);
      #pragma unroll
      for (int jj = 0; jj < 4; jj++) {
        u16x4 w = { f2bf(r0[jj]), f2bf(r1[jj]), f2bf(r2[jj]), f2bf(r3[jj]) };
        *(u16x4*)&BsT[d0 + jj][s0] = w;
      }
    }
    __syncthreads();
    #pragma unroll
    for (int kk = 0; kk < 2; kk++) {
      int kb = kk * 32 + ((lane >> 4) << 3);
      u16x8 a[4], bb[4];
      #pragma unroll
      for (int m = 0; m < 4; m++)
        a[m] = *(const u16x8*)&As[wr * 64 + m * 16 + (lane & 15)][kb];
      #pragma unroll
      for (int n = 0; n < 4; n++)
        bb[n] = *(const u16x8*)&BsT[wc * 64 + n * 16 + (lane & 15)][kb];
      #pragma unroll
      for (int m = 0; m < 4; m++)
        #pragma unroll
        for (int n = 0; n < 4; n++)
          acc[m][n] = mfma16(a[m], bb[n], acc[m][n]);
    }
  }
  #pragma unroll
  for (int m = 0; m < 4; m++)
    #pragma unroll
    for (int n = 0; n < 4; n++)
      #pragma unroll
      for (int j = 0; j < 4; j++) {
        int t = wr * 64 + m * 16 + ((lane >> 4) << 2) + j;
        int d = dblk * 128 + wc * 64 + n * 16 + (lane & 15);
        cout[((size_t)b * T_ + t) * D_ + d] = acc[m][n][j];
      }
}

// ---------------------------------------------------------------------------
// K4: attn_h[t][b][n] = tanh( sum_k [c,src][b][t][k] * W[n][k] )
// ---------------------------------------------------------------------------
__global__ __launch_bounds__(256, 2) void k_proj(
    const float* __restrict__ cbuf, const float* __restrict__ src,
    const float* __restrict__ w, float* __restrict__ out0)
{
  __shared__ unsigned short Ah[128][72], Bh[128][72];
  const int nblk = blockIdx.x, b = blockIdx.y;
  const int tid = threadIdx.x, lane = tid & 63, wave = tid >> 6;
  const int wr = wave >> 1, wc = wave & 1;

  f32x4 acc[4][4];
  #pragma unroll
  for (int m = 0; m < 4; m++)
    #pragma unroll
    for (int n = 0; n < 4; n++) acc[m][n] = (f32x4){0.f, 0.f, 0.f, 0.f};

  for (int k0 = 0; k0 < 2 * D_; k0 += 64) {
    const float* Asrc = (k0 < D_) ? (cbuf + (size_t)b * T_ * D_ + k0)
                                  : (src + (size_t)b * T_ * D_ + (k0 - D_));
    __syncthreads();
    #pragma unroll
    for (int j = 0; j < 8; j++) {
      int f4 = tid + 256 * j;
      int row = f4 >> 4, c4 = (f4 & 15) * 4;
      floatx4 va = *(const floatx4*)(Asrc + (size_t)row * D_ + c4);
      floatx4 vb = *(const floatx4*)(w + (size_t)(nblk * 128 + row) * (2 * D_) + k0 + c4);
      u16x4 ah, bh;
      #pragma unroll
      for (int i = 0; i < 4; i++) { ah[i] = f2bf(va[i]); bh[i] = f2bf(vb[i]); }
      *(u16x4*)&Ah[row][c4] = ah;
      *(u16x4*)&Bh[row][c4] = bh;
    }
    __syncthreads();
    #pragma unroll
    for (int kk = 0; kk < 2; kk++) {
      int kb = kk * 32 + ((lane >> 4) << 3);
      u16x8 a[4], bb[4];
      #pragma unroll
      for (int m = 0; m < 4; m++)
        a[m] = *(const u16x8*)&Ah[wr * 64 + m * 16 + (lane & 15)][kb];
      #pragma unroll
      for (int n = 0; n < 4; n++)
        bb[n] = *(const u16x8*)&Bh[wc * 64 + n * 16 + (lane & 15)][kb];
      #pragma unroll
      for (int m = 0; m < 4; m++)
        #pragma unroll
        for (int n = 0; n < 4; n++)
          acc[m][n] = mfma16(a[m], bb[n], acc[m][n]);
    }
  }
  #pragma unroll
  for (int m = 0; m < 4; m++)
    #pragma unroll
    for (int n = 0; n < 4; n++)
      #pragma unroll
      for (int j = 0; j < 4; j++) {
        int t = wr * 64 + m * 16 + ((lane >> 4) << 2) + j;
        int d = nblk * 128 + wc * 64 + n * 16 + (lane & 15);
        out0[(size_t)t * (B_ * D_) + (size_t)b * D_ + d] = tanhf(acc[m][n][j]);
      }
}

extern "C" void kernel_launch(void* const* d_in, const int* in_sizes, int n_in,
                              void* d_out, int out_size, void* d_ws, size_t ws_size,
                              hipStream_t stream) {
  const float* src = (const float*)d_in[0];   // [B][T][D]
  const float* mb  = (const float*)d_in[1];   // [B][S][D]
  const float* w   = (const float*)d_in[2];   // [D][2D]
  const int*   len = (const int*)d_in[3];     // [B]

  float* out0 = (float*)d_out;                       // attn_h [T][B][D]
  float* out1 = out0 + (size_t)T_ * B_ * D_;         // align  [T][B][S]

  float* logits = (float*)d_ws;                      // [B][T][S] fp32 (33.5 MB)
  float* cbuf   = logits + (size_t)B_ * T_ * S_;     // [B][T][D] fp32 (16.8 MB)

  k_align  <<<dim3(S_ / 128, B_), 256, 0, stream>>>(src, mb, logits);
  k_softmax<<<dim3(B_ * T_),      256, 0, stream>>>(logits, len, out1);
  k_pv     <<<dim3(D_ / 128, B_), 256, 0, stream>>>(logits, mb, cbuf);
  k_proj   <<<dim3(D_ / 128, B_ * T_ / 128), 256, 0, stream>>>(cbuf, src, w, out0);
}

// Round 2
// 252.530 us; speedup vs baseline: 1.6403x; 1.6403x over previous
//
#include <hip/hip_runtime.h>
#include <hip/hip_bf16.h>
#include <stdint.h>

#define B_ 32
#define T_ 128
#define S_ 2048
#define D_ 1024

typedef float floatx4 __attribute__((ext_vector_type(4)));
typedef float f32x4 __attribute__((ext_vector_type(4)));
typedef unsigned short u16x4 __attribute__((ext_vector_type(4)));
typedef unsigned short u16x8 __attribute__((ext_vector_type(8)));
typedef __bf16 bf16x8 __attribute__((ext_vector_type(8)));

__device__ __forceinline__ unsigned short f2bf(float x){
  __hip_bfloat16 h = __float2bfloat16(x);
  return __builtin_bit_cast(unsigned short, h);
}
__device__ __forceinline__ float bf2f(unsigned short u){
  __hip_bfloat16 h = __builtin_bit_cast(__hip_bfloat16, u);
  return __bfloat162float(h);
}
__device__ __forceinline__ f32x4 mfma16(u16x8 a, u16x8 b, f32x4 c){
  return __builtin_amdgcn_mfma_f32_16x16x32_bf16(
      __builtin_bit_cast(bf16x8, a), __builtin_bit_cast(bf16x8, b), c, 0, 0, 0);
}

// ---------------------------------------------------------------------------
// K1: logits[b][t][s] = sum_d src[b][t][d] * mb[b][s][d]
// Split-bf16 (hi/lo) x 3 MFMA. Tile 128(t) x 128(s), BK=64.
// 512 threads = 8 waves (2x4), wave tile 64x32. Register prefetch of next
// K-tile issued between barrier and MFMA phase (loads in flight over compute).
// grid(b, sblk): same-b blocks (sharing src panel) land on same XCD (id%8).
// ---------------------------------------------------------------------------
__global__ __launch_bounds__(512, 2) void k_align(
    const float* __restrict__ src, const float* __restrict__ mb,
    float* __restrict__ logits)
{
  __shared__ unsigned short Ah[128][72], Al[128][72], Bh[128][72], Bl[128][72];
  const int b = blockIdx.x, sblk = blockIdx.y;
  const int tid = threadIdx.x, lane = tid & 63, wave = tid >> 6;
  const int wr = wave >> 2, wc = wave & 3;
  const float* Ag = src + (size_t)b * T_ * D_;
  const float* Bg = mb + (size_t)b * S_ * D_ + (size_t)sblk * 128 * D_;

  f32x4 acc[4][2];
  #pragma unroll
  for (int m = 0; m < 4; m++)
    #pragma unroll
    for (int n = 0; n < 2; n++) acc[m][n] = (f32x4){0.f, 0.f, 0.f, 0.f};

  floatx4 ra[4], rb[4];
  #pragma unroll
  for (int j = 0; j < 4; j++) {
    int f4 = tid + 512 * j;              // [128 rows][16 float4]
    int row = f4 >> 4, c4 = (f4 & 15) * 4;
    ra[j] = *(const floatx4*)(Ag + (size_t)row * D_ + c4);
    rb[j] = *(const floatx4*)(Bg + (size_t)row * D_ + c4);
  }

  for (int k0 = 0; k0 < D_; k0 += 64) {
    // convert staged regs -> LDS
    #pragma unroll
    for (int j = 0; j < 4; j++) {
      int f4 = tid + 512 * j;
      int row = f4 >> 4, c4 = (f4 & 15) * 4;
      u16x4 ah, al, bh, bl;
      #pragma unroll
      for (int i = 0; i < 4; i++) {
        unsigned short h = f2bf(ra[j][i]); float hf = bf2f(h);
        ah[i] = h; al[i] = f2bf(ra[j][i] - hf);
        h = f2bf(rb[j][i]); hf = bf2f(h);
        bh[i] = h; bl[i] = f2bf(rb[j][i] - hf);
      }
      *(u16x4*)&Ah[row][c4] = ah;
      *(u16x4*)&Al[row][c4] = al;
      *(u16x4*)&Bh[row][c4] = bh;
      *(u16x4*)&Bl[row][c4] = bl;
    }
    __syncthreads();
    // prefetch next K-tile (in flight during MFMA phase)
    if (k0 + 64 < D_) {
      #pragma unroll
      for (int j = 0; j < 4; j++) {
        int f4 = tid + 512 * j;
        int row = f4 >> 4, c4 = (f4 & 15) * 4;
        ra[j] = *(const floatx4*)(Ag + (size_t)row * D_ + (k0 + 64) + c4);
        rb[j] = *(const floatx4*)(Bg + (size_t)row * D_ + (k0 + 64) + c4);
      }
    }
    #pragma unroll
    for (int kk = 0; kk < 2; kk++) {
      int kb = kk * 32 + ((lane >> 4) << 3);
      u16x8 a_h[4], a_l[4], b_h[2], b_l[2];
      #pragma unroll
      for (int m = 0; m < 4; m++) {
        int r = wr * 64 + m * 16 + (lane & 15);
        a_h[m] = *(const u16x8*)&Ah[r][kb];
        a_l[m] = *(const u16x8*)&Al[r][kb];
      }
      #pragma unroll
      for (int n = 0; n < 2; n++) {
        int r = wc * 32 + n * 16 + (lane & 15);
        b_h[n] = *(const u16x8*)&Bh[r][kb];
        b_l[n] = *(const u16x8*)&Bl[r][kb];
      }
      #pragma unroll
      for (int m = 0; m < 4; m++)
        #pragma unroll
        for (int n = 0; n < 2; n++) {
          acc[m][n] = mfma16(a_h[m], b_h[n], acc[m][n]);
          acc[m][n] = mfma16(a_h[m], b_l[n], acc[m][n]);
          acc[m][n] = mfma16(a_l[m], b_h[n], acc[m][n]);
        }
    }
    __syncthreads();
  }
  #pragma unroll
  for (int m = 0; m < 4; m++)
    #pragma unroll
    for (int n = 0; n < 2; n++)
      #pragma unroll
      for (int j = 0; j < 4; j++) {
        int t = wr * 64 + m * 16 + ((lane >> 4) << 2) + j;
        int s = sblk * 128 + wc * 32 + n * 16 + (lane & 15);
        logits[((size_t)b * T_ + t) * S_ + s] = acc[m][n][j];
      }
}

// ---------------------------------------------------------------------------
// K2: masked softmax per (b,t) row; writes p in-place over logits (for K3)
// and transposed to out1[t][b][s].
// ---------------------------------------------------------------------------
__global__ __launch_bounds__(256) void k_softmax(
    float* __restrict__ logits, const int* __restrict__ lens,
    float* __restrict__ out1)
{
  const int bt = blockIdx.x;
  const int b = bt >> 7, t = bt & 127;
  const int probe = lens[1];               // 0 iff int64 layout (lens>=1)
  const int len = (probe == 0) ? lens[2 * b] : lens[b];
  float* row = logits + (size_t)bt * S_;
  const int tid = threadIdx.x, lane = tid & 63, wave = tid >> 6;

  floatx4 v[2];
  float mx = -3.0e38f;
  #pragma unroll
  for (int j = 0; j < 2; j++) {
    int f4 = tid + 256 * j;
    v[j] = *(const floatx4*)(row + f4 * 4);
    #pragma unroll
    for (int i = 0; i < 4; i++) {
      int s = f4 * 4 + i;
      if (s < len) mx = fmaxf(mx, v[j][i]);
    }
  }
  #pragma unroll
  for (int off = 1; off < 64; off <<= 1) mx = fmaxf(mx, __shfl_xor(mx, off));
  __shared__ float red[8];
  if (lane == 0) red[wave] = mx;
  __syncthreads();
  mx = fmaxf(fmaxf(red[0], red[1]), fmaxf(red[2], red[3]));

  float sum = 0.f;
  floatx4 e[2];
  #pragma unroll
  for (int j = 0; j < 2; j++) {
    int f4 = tid + 256 * j;
    #pragma unroll
    for (int i = 0; i < 4; i++) {
      int s = f4 * 4 + i;
      float ee = (s < len) ? __expf(v[j][i] - mx) : 0.f;
      e[j][i] = ee; sum += ee;
    }
  }
  #pragma unroll
  for (int off = 1; off < 64; off <<= 1) sum += __shfl_xor(sum, off);
  if (lane == 0) red[4 + wave] = sum;
  __syncthreads();
  sum = red[4] + red[5] + red[6] + red[7];
  const float inv = 1.0f / sum;

  float* orow = out1 + ((size_t)t * B_ + b) * S_;
  #pragma unroll
  for (int j = 0; j < 2; j++) {
    int f4 = tid + 256 * j;
    floatx4 o;
    #pragma unroll
    for (int i = 0; i < 4; i++) o[i] = e[j][i] * inv;
    *(floatx4*)(row + f4 * 4) = o;
    *(floatx4*)(orow + f4 * 4) = o;
  }
}

// ---------------------------------------------------------------------------
// K3: c[b][t][d] = sum_s p[b][t][s] * mb[b][s][d].
// 512 threads, 8 waves (2x4), reg prefetch. grid(b, dblk): same-b on same XCD.
// ---------------------------------------------------------------------------
__global__ __launch_bounds__(512, 2) void k_pv(
    const float* __restrict__ p, const float* __restrict__ mb,
    float* __restrict__ cout)
{
  __shared__ unsigned short As[128][72];   // [t][s]
  __shared__ unsigned short BsT[128][72];  // [d][s]
  const int b = blockIdx.x, dblk = blockIdx.y;
  const int tid = threadIdx.x, lane = tid & 63, wave = tid >> 6;
  const int wr = wave >> 2, wc = wave & 3;
  const float* Pg = p + (size_t)b * T_ * S_;
  const float* Bg = mb + (size_t)b * S_ * D_ + dblk * 128;

  f32x4 acc[4][2];
  #pragma unroll
  for (int m = 0; m < 4; m++)
    #pragma unroll
    for (int n = 0; n < 2; n++) acc[m][n] = (f32x4){0.f, 0.f, 0.f, 0.f};

  const int gs = tid & 15, gd = tid >> 4;  // transpose group: 4s x 4d
  const int s0 = gs * 4, d0 = gd * 4;

  floatx4 ra[4], rb[4];
  #pragma unroll
  for (int j = 0; j < 4; j++) {
    int f4 = tid + 512 * j;
    int row = f4 >> 4, c4 = (f4 & 15) * 4;
    ra[j] = *(const floatx4*)(Pg + (size_t)row * S_ + c4);
    rb[j] = *(const floatx4*)(Bg + (size_t)(s0 + j) * D_ + d0);
  }

  for (int k0 = 0; k0 < S_; k0 += 64) {
    #pragma unroll
    for (int j = 0; j < 4; j++) {
      int f4 = tid + 512 * j;
      int row = f4 >> 4, c4 = (f4 & 15) * 4;
      u16x4 ah;
      #pragma unroll
      for (int i = 0; i < 4; i++) ah[i] = f2bf(ra[j][i]);
      *(u16x4*)&As[row][c4] = ah;
    }
    #pragma unroll
    for (int jj = 0; jj < 4; jj++) {
      u16x4 w = { f2bf(rb[0][jj]), f2bf(rb[1][jj]), f2bf(rb[2][jj]), f2bf(rb[3][jj]) };
      *(u16x4*)&BsT[d0 + jj][s0] = w;
    }
    __syncthreads();
    if (k0 + 64 < S_) {
      #pragma unroll
      for (int j = 0; j < 4; j++) {
        int f4 = tid + 512 * j;
        int row = f4 >> 4, c4 = (f4 & 15) * 4;
        ra[j] = *(const floatx4*)(Pg + (size_t)row * S_ + (k0 + 64) + c4);
        rb[j] = *(const floatx4*)(Bg + (size_t)(k0 + 64 + s0 + j) * D_ + d0);
      }
    }
    #pragma unroll
    for (int kk = 0; kk < 2; kk++) {
      int kb = kk * 32 + ((lane >> 4) << 3);
      u16x8 a[4], bb[2];
      #pragma unroll
      for (int m = 0; m < 4; m++)
        a[m] = *(const u16x8*)&As[wr * 64 + m * 16 + (lane & 15)][kb];
      #pragma unroll
      for (int n = 0; n < 2; n++)
        bb[n] = *(const u16x8*)&BsT[wc * 32 + n * 16 + (lane & 15)][kb];
      #pragma unroll
      for (int m = 0; m < 4; m++)
        #pragma unroll
        for (int n = 0; n < 2; n++)
          acc[m][n] = mfma16(a[m], bb[n], acc[m][n]);
    }
    __syncthreads();
  }
  #pragma unroll
  for (int m = 0; m < 4; m++)
    #pragma unroll
    for (int n = 0; n < 2; n++)
      #pragma unroll
      for (int j = 0; j < 4; j++) {
        int t = wr * 64 + m * 16 + ((lane >> 4) << 2) + j;
        int d = dblk * 128 + wc * 32 + n * 16 + (lane & 15);
        cout[((size_t)b * T_ + t) * D_ + d] = acc[m][n][j];
      }
}

// ---------------------------------------------------------------------------
// K4: attn_h[t][b][n] = tanh( sum_k [c,src][b][t][k] * W[n][k] )
// 512 threads, 8 waves, reg prefetch. grid(b, nblk): same-b (sharing the
// [c,src] panel) on same XCD; W panels via L3.
// ---------------------------------------------------------------------------
__global__ __launch_bounds__(512, 2) void k_proj(
    const float* __restrict__ cbuf, const float* __restrict__ src,
    const float* __restrict__ w, float* __restrict__ out0)
{
  __shared__ unsigned short Ah[128][72], Bh[128][72];
  const int b = blockIdx.x, nblk = blockIdx.y;
  const int tid = threadIdx.x, lane = tid & 63, wave = tid >> 6;
  const int wr = wave >> 2, wc = wave & 3;
  const float* Ca = cbuf + (size_t)b * T_ * D_;
  const float* Sa = src + (size_t)b * T_ * D_;

  f32x4 acc[4][2];
  #pragma unroll
  for (int m = 0; m < 4; m++)
    #pragma unroll
    for (int n = 0; n < 2; n++) acc[m][n] = (f32x4){0.f, 0.f, 0.f, 0.f};

  floatx4 ra[4], rb[4];
  #pragma unroll
  for (int j = 0; j < 4; j++) {
    int f4 = tid + 512 * j;
    int row = f4 >> 4, c4 = (f4 & 15) * 4;
    ra[j] = *(const floatx4*)(Ca + (size_t)row * D_ + c4);
    rb[j] = *(const floatx4*)(w + (size_t)(nblk * 128 + row) * (2 * D_) + c4);
  }

  for (int k0 = 0; k0 < 2 * D_; k0 += 64) {
    #pragma unroll
    for (int j = 0; j < 4; j++) {
      int f4 = tid + 512 * j;
      int row = f4 >> 4, c4 = (f4 & 15) * 4;
      u16x4 ah, bh;
      #pragma unroll
      for (int i = 0; i < 4; i++) { ah[i] = f2bf(ra[j][i]); bh[i] = f2bf(rb[j][i]); }
      *(u16x4*)&Ah[row][c4] = ah;
      *(u16x4*)&Bh[row][c4] = bh;
    }
    __syncthreads();
    if (k0 + 64 < 2 * D_) {
      int kn = k0 + 64;
      const float* Asrc = (kn < D_) ? (Ca + kn) : (Sa + (kn - D_));
      #pragma unroll
      for (int j = 0; j < 4; j++) {
        int f4 = tid + 512 * j;
        int row = f4 >> 4, c4 = (f4 & 15) * 4;
        ra[j] = *(const floatx4*)(Asrc + (size_t)row * D_ + c4);
        rb[j] = *(const floatx4*)(w + (size_t)(nblk * 128 + row) * (2 * D_) + kn + c4);
      }
    }
    #pragma unroll
    for (int kk = 0; kk < 2; kk++) {
      int kb = kk * 32 + ((lane >> 4) << 3);
      u16x8 a[4], bb[2];
      #pragma unroll
      for (int m = 0; m < 4; m++)
        a[m] = *(const u16x8*)&Ah[wr * 64 + m * 16 + (lane & 15)][kb];
      #pragma unroll
      for (int n = 0; n < 2; n++)
        bb[n] = *(const u16x8*)&Bh[wc * 32 + n * 16 + (lane & 15)][kb];
      #pragma unroll
      for (int m = 0; m < 4; m++)
        #pragma unroll
        for (int n = 0; n < 2; n++)
          acc[m][n] = mfma16(a[m], bb[n], acc[m][n]);
    }
    __syncthreads();
  }
  #pragma unroll
  for (int m = 0; m < 4; m++)
    #pragma unroll
    for (int n = 0; n < 2; n++)
      #pragma unroll
      for (int j = 0; j < 4; j++) {
        int t = wr * 64 + m * 16 + ((lane >> 4) << 2) + j;
        int d = nblk * 128 + wc * 32 + n * 16 + (lane & 15);
        out0[(size_t)t * (B_ * D_) + (size_t)b * D_ + d] = tanhf(acc[m][n][j]);
      }
}

extern "C" void kernel_launch(void* const* d_in, const int* in_sizes, int n_in,
                              void* d_out, int out_size, void* d_ws, size_t ws_size,
                              hipStream_t stream) {
  const float* src = (const float*)d_in[0];   // [B][T][D]
  const float* mb  = (const float*)d_in[1];   // [B][S][D]
  const float* w   = (const float*)d_in[2];   // [D][2D]
  const int*   len = (const int*)d_in[3];     // [B]

  float* out0 = (float*)d_out;                       // attn_h [T][B][D]
  float* out1 = out0 + (size_t)T_ * B_ * D_;         // align  [T][B][S]

  float* logits = (float*)d_ws;                      // [B][T][S] fp32
  float* cbuf   = logits + (size_t)B_ * T_ * S_;     // [B][T][D] fp32

  k_align  <<<dim3(B_, S_ / 128), 512, 0, stream>>>(src, mb, logits);
  k_softmax<<<dim3(B_ * T_),      256, 0, stream>>>(logits, len, out1);
  k_pv     <<<dim3(B_, D_ / 128), 512, 0, stream>>>(logits, mb, cbuf);
  k_proj   <<<dim3(B_, D_ / 128), 512, 0, stream>>>(cbuf, src, w, out0);
}

// Round 4
// 220.205 us; speedup vs baseline: 1.8810x; 1.1468x over previous
//
#include <hip/hip_runtime.h>
#include <hip/hip_bf16.h>
#include <stdint.h>

#define B_ 32
#define T_ 128
#define S_ 2048
#define D_ 1024

typedef float floatx4 __attribute__((ext_vector_type(4)));
typedef float f32x4 __attribute__((ext_vector_type(4)));
typedef unsigned short u16x4 __attribute__((ext_vector_type(4)));
typedef unsigned short u16x8 __attribute__((ext_vector_type(8)));
typedef __bf16 bf16x8 __attribute__((ext_vector_type(8)));

__device__ __forceinline__ unsigned short f2bf(float x){
  __hip_bfloat16 h = __float2bfloat16(x);
  return __builtin_bit_cast(unsigned short, h);
}
__device__ __forceinline__ float bf2f(unsigned short u){
  __hip_bfloat16 h = __builtin_bit_cast(__hip_bfloat16, u);
  return __bfloat162float(h);
}
__device__ __forceinline__ f32x4 mfma16(u16x8 a, u16x8 b, f32x4 c){
  return __builtin_amdgcn_mfma_f32_16x16x32_bf16(
      __builtin_bit_cast(bf16x8, a), __builtin_bit_cast(bf16x8, b), c, 0, 0, 0);
}

// ---------------------------------------------------------------------------
// K1: logits[b][t][s] = sum_d src[b][t][d] * mb[b][s][d]
// Split-bf16 (RNE hi/lo) x 3 MFMA. Tile 128(t) x 128(s), BK=32.
// 8 waves (2x4), wave tile 64x32. Structure identical to the round-2
// (verified) version; only BK 64->32 so LDS = 40 KB -> 2 blocks/CU.
// Latency hidden by cross-block TLP instead of intra-block pipelining.
// ---------------------------------------------------------------------------
__global__ __launch_bounds__(512, 4) void k_align(
    const float* __restrict__ src, const float* __restrict__ mb,
    float* __restrict__ logits)
{
  __shared__ unsigned short Ah[128][40], Al[128][40], Bh[128][40], Bl[128][40];
  const int b = blockIdx.x, sblk = blockIdx.y;
  const int tid = threadIdx.x, lane = tid & 63, wave = tid >> 6;
  const int wr = wave >> 2, wc = wave & 3;
  const float* Ag = src + (size_t)b * T_ * D_;
  const float* Bg = mb + (size_t)b * S_ * D_ + (size_t)sblk * 128 * D_;

  f32x4 acc[4][2];
  #pragma unroll
  for (int m = 0; m < 4; m++)
    #pragma unroll
    for (int n = 0; n < 2; n++) acc[m][n] = (f32x4){0.f, 0.f, 0.f, 0.f};

  // staging: [128 rows][8 float4] = 1024 float4 per panel, 2 per thread
  floatx4 ra[2], rb[2];
  #pragma unroll
  for (int j = 0; j < 2; j++) {
    int f4 = tid + 512 * j;
    int row = f4 >> 3, c4 = (f4 & 7) * 4;
    ra[j] = *(const floatx4*)(Ag + (size_t)row * D_ + c4);
    rb[j] = *(const floatx4*)(Bg + (size_t)row * D_ + c4);
  }

  for (int k0 = 0; k0 < D_; k0 += 32) {
    // convert staged regs -> LDS (RNE hi/lo split, same math as round 2)
    #pragma unroll
    for (int j = 0; j < 2; j++) {
      int f4 = tid + 512 * j;
      int row = f4 >> 3, c4 = (f4 & 7) * 4;
      u16x4 ah, al, bh, bl;
      #pragma unroll
      for (int i = 0; i < 4; i++) {
        unsigned short h = f2bf(ra[j][i]); float hf = bf2f(h);
        ah[i] = h; al[i] = f2bf(ra[j][i] - hf);
        h = f2bf(rb[j][i]); hf = bf2f(h);
        bh[i] = h; bl[i] = f2bf(rb[j][i] - hf);
      }
      *(u16x4*)&Ah[row][c4] = ah;
      *(u16x4*)&Al[row][c4] = al;
      *(u16x4*)&Bh[row][c4] = bh;
      *(u16x4*)&Bl[row][c4] = bl;
    }
    __syncthreads();
    // prefetch next K-tile (in flight during MFMA phase)
    if (k0 + 32 < D_) {
      #pragma unroll
      for (int j = 0; j < 2; j++) {
        int f4 = tid + 512 * j;
        int row = f4 >> 3, c4 = (f4 & 7) * 4;
        ra[j] = *(const floatx4*)(Ag + (size_t)row * D_ + (k0 + 32) + c4);
        rb[j] = *(const floatx4*)(Bg + (size_t)row * D_ + (k0 + 32) + c4);
      }
    }
    {
      const int kb = (lane >> 4) << 3;
      u16x8 a_h[4], a_l[4], b_h[2], b_l[2];
      #pragma unroll
      for (int m = 0; m < 4; m++) {
        int r = wr * 64 + m * 16 + (lane & 15);
        a_h[m] = *(const u16x8*)&Ah[r][kb];
        a_l[m] = *(const u16x8*)&Al[r][kb];
      }
      #pragma unroll
      for (int n = 0; n < 2; n++) {
        int r = wc * 32 + n * 16 + (lane & 15);
        b_h[n] = *(const u16x8*)&Bh[r][kb];
        b_l[n] = *(const u16x8*)&Bl[r][kb];
      }
      #pragma unroll
      for (int m = 0; m < 4; m++)
        #pragma unroll
        for (int n = 0; n < 2; n++) {
          acc[m][n] = mfma16(a_h[m], b_h[n], acc[m][n]);
          acc[m][n] = mfma16(a_h[m], b_l[n], acc[m][n]);
          acc[m][n] = mfma16(a_l[m], b_h[n], acc[m][n]);
        }
    }
    __syncthreads();
  }
  #pragma unroll
  for (int m = 0; m < 4; m++)
    #pragma unroll
    for (int n = 0; n < 2; n++)
      #pragma unroll
      for (int j = 0; j < 4; j++) {
        int t = wr * 64 + m * 16 + ((lane >> 4) << 2) + j;
        int s = sblk * 128 + wc * 32 + n * 16 + (lane & 15);
        logits[((size_t)b * T_ + t) * S_ + s] = acc[m][n][j];
      }
}

// ---------------------------------------------------------------------------
// K2: masked softmax per (b,t) row; writes p in-place over logits (for K3)
// and transposed to out1[t][b][s].
// ---------------------------------------------------------------------------
__global__ __launch_bounds__(256) void k_softmax(
    float* __restrict__ logits, const int* __restrict__ lens,
    float* __restrict__ out1)
{
  const int bt = blockIdx.x;
  const int b = bt >> 7, t = bt & 127;
  const int probe = lens[1];               // 0 iff int64 layout (lens>=1)
  const int len = (probe == 0) ? lens[2 * b] : lens[b];
  float* row = logits + (size_t)bt * S_;
  const int tid = threadIdx.x, lane = tid & 63, wave = tid >> 6;

  floatx4 v[2];
  float mx = -3.0e38f;
  #pragma unroll
  for (int j = 0; j < 2; j++) {
    int f4 = tid + 256 * j;
    v[j] = *(const floatx4*)(row + f4 * 4);
    #pragma unroll
    for (int i = 0; i < 4; i++) {
      int s = f4 * 4 + i;
      if (s < len) mx = fmaxf(mx, v[j][i]);
    }
  }
  #pragma unroll
  for (int off = 1; off < 64; off <<= 1) mx = fmaxf(mx, __shfl_xor(mx, off));
  __shared__ float red[8];
  if (lane == 0) red[wave] = mx;
  __syncthreads();
  mx = fmaxf(fmaxf(red[0], red[1]), fmaxf(red[2], red[3]));

  float sum = 0.f;
  floatx4 e[2];
  #pragma unroll
  for (int j = 0; j < 2; j++) {
    int f4 = tid + 256 * j;
    #pragma unroll
    for (int i = 0; i < 4; i++) {
      int s = f4 * 4 + i;
      float ee = (s < len) ? __expf(v[j][i] - mx) : 0.f;
      e[j][i] = ee; sum += ee;
    }
  }
  #pragma unroll
  for (int off = 1; off < 64; off <<= 1) sum += __shfl_xor(sum, off);
  if (lane == 0) red[4 + wave] = sum;
  __syncthreads();
  sum = red[4] + red[5] + red[6] + red[7];
  const float inv = 1.0f / sum;

  float* orow = out1 + ((size_t)t * B_ + b) * S_;
  #pragma unroll
  for (int j = 0; j < 2; j++) {
    int f4 = tid + 256 * j;
    floatx4 o;
    #pragma unroll
    for (int i = 0; i < 4; i++) o[i] = e[j][i] * inv;
    *(floatx4*)(row + f4 * 4) = o;
    *(floatx4*)(orow + f4 * 4) = o;
  }
}

// ---------------------------------------------------------------------------
// K3: c[b][t][d] = sum_s p[b][t][s] * mb[b][s][d].
// 512 threads, 8 waves (2x4), reg prefetch. grid(b, dblk): same-b on same XCD.
// ---------------------------------------------------------------------------
__global__ __launch_bounds__(512, 2) void k_pv(
    const float* __restrict__ p, const float* __restrict__ mb,
    float* __restrict__ cout)
{
  __shared__ unsigned short As[128][72];   // [t][s]
  __shared__ unsigned short BsT[128][72];  // [d][s]
  const int b = blockIdx.x, dblk = blockIdx.y;
  const int tid = threadIdx.x, lane = tid & 63, wave = tid >> 6;
  const int wr = wave >> 2, wc = wave & 3;
  const float* Pg = p + (size_t)b * T_ * S_;
  const float* Bg = mb + (size_t)b * S_ * D_ + dblk * 128;

  f32x4 acc[4][2];
  #pragma unroll
  for (int m = 0; m < 4; m++)
    #pragma unroll
    for (int n = 0; n < 2; n++) acc[m][n] = (f32x4){0.f, 0.f, 0.f, 0.f};

  const int gs = tid & 15, gd = tid >> 4;  // transpose group: 4s x 4d
  const int s0 = gs * 4, d0 = gd * 4;

  floatx4 ra[4], rb[4];
  #pragma unroll
  for (int j = 0; j < 4; j++) {
    int f4 = tid + 512 * j;
    int row = f4 >> 4, c4 = (f4 & 15) * 4;
    ra[j] = *(const floatx4*)(Pg + (size_t)row * S_ + c4);
    rb[j] = *(const floatx4*)(Bg + (size_t)(s0 + j) * D_ + d0);
  }

  for (int k0 = 0; k0 < S_; k0 += 64) {
    #pragma unroll
    for (int j = 0; j < 4; j++) {
      int f4 = tid + 512 * j;
      int row = f4 >> 4, c4 = (f4 & 15) * 4;
      u16x4 ah;
      #pragma unroll
      for (int i = 0; i < 4; i++) ah[i] = f2bf(ra[j][i]);
      *(u16x4*)&As[row][c4] = ah;
    }
    #pragma unroll
    for (int jj = 0; jj < 4; jj++) {
      u16x4 w = { f2bf(rb[0][jj]), f2bf(rb[1][jj]), f2bf(rb[2][jj]), f2bf(rb[3][jj]) };
      *(u16x4*)&BsT[d0 + jj][s0] = w;
    }
    __syncthreads();
    if (k0 + 64 < S_) {
      #pragma unroll
      for (int j = 0; j < 4; j++) {
        int f4 = tid + 512 * j;
        int row = f4 >> 4, c4 = (f4 & 15) * 4;
        ra[j] = *(const floatx4*)(Pg + (size_t)row * S_ + (k0 + 64) + c4);
        rb[j] = *(const floatx4*)(Bg + (size_t)(k0 + 64 + s0 + j) * D_ + d0);
      }
    }
    #pragma unroll
    for (int kk = 0; kk < 2; kk++) {
      int kb = kk * 32 + ((lane >> 4) << 3);
      u16x8 a[4], bb[2];
      #pragma unroll
      for (int m = 0; m < 4; m++)
        a[m] = *(const u16x8*)&As[wr * 64 + m * 16 + (lane & 15)][kb];
      #pragma unroll
      for (int n = 0; n < 2; n++)
        bb[n] = *(const u16x8*)&BsT[wc * 32 + n * 16 + (lane & 15)][kb];
      #pragma unroll
      for (int m = 0; m < 4; m++)
        #pragma unroll
        for (int n = 0; n < 2; n++)
          acc[m][n] = mfma16(a[m], bb[n], acc[m][n]);
    }
    __syncthreads();
  }
  #pragma unroll
  for (int m = 0; m < 4; m++)
    #pragma unroll
    for (int n = 0; n < 2; n++)
      #pragma unroll
      for (int j = 0; j < 4; j++) {
        int t = wr * 64 + m * 16 + ((lane >> 4) << 2) + j;
        int d = dblk * 128 + wc * 32 + n * 16 + (lane & 15);
        cout[((size_t)b * T_ + t) * D_ + d] = acc[m][n][j];
      }
}

// ---------------------------------------------------------------------------
// K4: attn_h[t][b][n] = tanh( sum_k [c,src][b][t][k] * W[n][k] )
// ---------------------------------------------------------------------------
__global__ __launch_bounds__(512, 2) void k_proj(
    const float* __restrict__ cbuf, const float* __restrict__ src,
    const float* __restrict__ w, float* __restrict__ out0)
{
  __shared__ unsigned short Ah[128][72], Bh[128][72];
  const int b = blockIdx.x, nblk = blockIdx.y;
  const int tid = threadIdx.x, lane = tid & 63, wave = tid >> 6;
  const int wr = wave >> 2, wc = wave & 3;
  const float* Ca = cbuf + (size_t)b * T_ * D_;
  const float* Sa = src + (size_t)b * T_ * D_;

  f32x4 acc[4][2];
  #pragma unroll
  for (int m = 0; m < 4; m++)
    #pragma unroll
    for (int n = 0; n < 2; n++) acc[m][n] = (f32x4){0.f, 0.f, 0.f, 0.f};

  floatx4 ra[4], rb[4];
  #pragma unroll
  for (int j = 0; j < 4; j++) {
    int f4 = tid + 512 * j;
    int row = f4 >> 4, c4 = (f4 & 15) * 4;
    ra[j] = *(const floatx4*)(Ca + (size_t)row * D_ + c4);
    rb[j] = *(const floatx4*)(w + (size_t)(nblk * 128 + row) * (2 * D_) + c4);
  }

  for (int k0 = 0; k0 < 2 * D_; k0 += 64) {
    #pragma unroll
    for (int j = 0; j < 4; j++) {
      int f4 = tid + 512 * j;
      int row = f4 >> 4, c4 = (f4 & 15) * 4;
      u16x4 ah, bh;
      #pragma unroll
      for (int i = 0; i < 4; i++) { ah[i] = f2bf(ra[j][i]); bh[i] = f2bf(rb[j][i]); }
      *(u16x4*)&Ah[row][c4] = ah;
      *(u16x4*)&Bh[row][c4] = bh;
    }
    __syncthreads();
    if (k0 + 64 < 2 * D_) {
      int kn = k0 + 64;
      const float* Asrc = (kn < D_) ? (Ca + kn) : (Sa + (kn - D_));
      #pragma unroll
      for (int j = 0; j < 4; j++) {
        int f4 = tid + 512 * j;
        int row = f4 >> 4, c4 = (f4 & 15) * 4;
        ra[j] = *(const floatx4*)(Asrc + (size_t)row * D_ + c4);
        rb[j] = *(const floatx4*)(w + (size_t)(nblk * 128 + row) * (2 * D_) + kn + c4);
      }
    }
    #pragma unroll
    for (int kk = 0; kk < 2; kk++) {
      int kb = kk * 32 + ((lane >> 4) << 3);
      u16x8 a[4], bb[2];
      #pragma unroll
      for (int m = 0; m < 4; m++)
        a[m] = *(const u16x8*)&Ah[wr * 64 + m * 16 + (lane & 15)][kb];
      #pragma unroll
      for (int n = 0; n < 2; n++)
        bb[n] = *(const u16x8*)&Bh[wc * 32 + n * 16 + (lane & 15)][kb];
      #pragma unroll
      for (int m = 0; m < 4; m++)
        #pragma unroll
        for (int n = 0; n < 2; n++)
          acc[m][n] = mfma16(a[m], bb[n], acc[m][n]);
    }
    __syncthreads();
  }
  #pragma unroll
  for (int m = 0; m < 4; m++)
    #pragma unroll
    for (int n = 0; n < 2; n++)
      #pragma unroll
      for (int j = 0; j < 4; j++) {
        int t = wr * 64 + m * 16 + ((lane >> 4) << 2) + j;
        int d = nblk * 128 + wc * 32 + n * 16 + (lane & 15);
        out0[(size_t)t * (B_ * D_) + (size_t)b * D_ + d] = tanhf(acc[m][n][j]);
      }
}

extern "C" void kernel_launch(void* const* d_in, const int* in_sizes, int n_in,
                              void* d_out, int out_size, void* d_ws, size_t ws_size,
                              hipStream_t stream) {
  const float* src = (const float*)d_in[0];   // [B][T][D]
  const float* mb  = (const float*)d_in[1];   // [B][S][D]
  const float* w   = (const float*)d_in[2];   // [D][2D]
  const int*   len = (const int*)d_in[3];     // [B]

  float* out0 = (float*)d_out;                       // attn_h [T][B][D]
  float* out1 = out0 + (size_t)T_ * B_ * D_;         // align  [T][B][S]

  float* logits = (float*)d_ws;                      // [B][T][S] fp32
  float* cbuf   = logits + (size_t)B_ * T_ * S_;     // [B][T][D] fp32

  k_align  <<<dim3(B_, S_ / 128), 512, 0, stream>>>(src, mb, logits);
  k_softmax<<<dim3(B_ * T_),      256, 0, stream>>>(logits, len, out1);
  k_pv     <<<dim3(B_, D_ / 128), 512, 0, stream>>>(logits, mb, cbuf);
  k_proj   <<<dim3(B_, D_ / 128), 512, 0, stream>>>(cbuf, src, w, out0);
}